// Round 8
// baseline (138.229 us; speedup 1.0000x reference)
//
#include <hip/hip_runtime.h>
#include <hip/hip_fp16.h>

#define DIM 1024
#define NB 8
#define CBLK 8
#define LSTRIDE 10  // half2 per row: 8 + 2 pad -> 40 B row; 40 KB tile, 4 blocks/CU

typedef float vfloat4 __attribute__((ext_vector_type(4)));  // native vec for nontemporal builtin

// LDS tile: 1024 rows x 8 (+2 pad) half2 = 40960 B; 4 blocks = 160 KB = full CU.
__device__ __forceinline__ int lidx(int r, int c) {
  return r * LSTRIDE + c;
}

__device__ __forceinline__ unsigned rflu(unsigned x) {
  return (unsigned)__builtin_amdgcn_readfirstlane((int)x);
}
__device__ __forceinline__ unsigned h2u(__half2 h) {
  union { __half2 h; unsigned u; } c; c.h = h; return c.u;
}
__device__ __forceinline__ __half2 u2h(unsigned u) {
  union { unsigned u; __half2 h; } c; c.u = u; return c.h;
}
// swap halves: (a,b) -> (b,a)
__device__ __forceinline__ __half2 h2swap(__half2 x) {
  unsigned u = h2u(x);
  return u2h((u >> 16) | (u << 16));
}

struct __align__(16) H2x4 { __half2 h[4]; };

// Packed complex 4x4 matvec, in place along `stride`. half2 = (re, im).
// y = W x : Wre2*x + Wimn*swap(x), Wre2=(Wre,Wre), Wimn=(-Wim,+Wim)
__device__ __forceinline__ void mv4p(__half2* v, const int stride,
                                     const unsigned (&Wre2)[4][4],
                                     const unsigned (&Wimn)[4][4]) {
  __half2 x0 = v[0], x1 = v[stride], x2 = v[2 * stride], x3 = v[3 * stride];
  __half2 s0 = h2swap(x0), s1 = h2swap(x1), s2 = h2swap(x2), s3 = h2swap(x3);
  #pragma unroll
  for (int p = 0; p < 4; ++p) {
    __half2 a = u2h(Wre2[p][0]) * x0;
    a = __hfma2(u2h(Wimn[p][0]), s0, a);
    a = __hfma2(u2h(Wre2[p][2]), x2, a);
    a = __hfma2(u2h(Wimn[p][2]), s2, a);
    __half2 b = u2h(Wre2[p][1]) * x1;
    b = __hfma2(u2h(Wimn[p][1]), s1, b);
    b = __hfma2(u2h(Wre2[p][3]), x3, b);
    b = __hfma2(u2h(Wimn[p][3]), s3, b);
    v[p * stride] = a + b;
  }
}

// Real-input packed variant: x[k] = (re,re); Wri=(Wre,Wim);
// y[p] = sum_k (Wre*re, Wim*re) — one packed op per term.
__device__ __forceinline__ void mv4rp(const __half2* x, __half2* y,
                                      const unsigned (&Wri)[4][4]) {
  #pragma unroll
  for (int p = 0; p < 4; ++p) {
    __half2 a = u2h(Wri[p][0]) * x[0];
    a = __hfma2(u2h(Wri[p][2]), x[2], a);
    __half2 b = u2h(Wri[p][1]) * x[1];
    b = __hfma2(u2h(Wri[p][3]), x[3], b);
    y[p] = a + b;
  }
}

// Build W = V^dagger (pass 0) or V^T (pass 1); packed half2 tables in SGPRs.
__device__ void compute_W(const float* __restrict__ wgt, int pass,
                          unsigned (&Wre2)[4][4], unsigned (&Wimn)[4][4],
                          unsigned (&Wri)[4][4]) {
  const float WMUL = 0.6324555320336759f;  // sqrt(0.4)
  float ca[6], sa[6];
  #pragma unroll
  for (int i = 0; i < 6; ++i) {
    float h = wgt[i] * (0.5f * WMUL);
    ca[i] = cosf(h);
    sa[i] = sinf(h);
  }
  float R01[4][4], R34[4][4];
  {
    float a0[2][2] = {{ca[0], -sa[0]}, {sa[0], ca[0]}};
    float b0[2][2] = {{ca[1], -sa[1]}, {sa[1], ca[1]}};
    float a1[2][2] = {{ca[3], -sa[3]}, {sa[3], ca[3]}};
    float b1[2][2] = {{ca[4], -sa[4]}, {sa[4], ca[4]}};
    #pragma unroll
    for (int i = 0; i < 4; ++i)
      #pragma unroll
      for (int j = 0; j < 4; ++j) {
        R01[i][j] = a0[i >> 1][j >> 1] * b0[i & 1][j & 1];
        R34[i][j] = a1[i >> 1][j >> 1] * b1[i & 1][j & 1];
      }
  }
  float M2re[4][4], M2im[4][4];
  #pragma unroll
  for (int k = 0; k < 4; ++k)
    #pragma unroll
    for (int j = 0; j < 4; ++j) {
      M2re[k][j] = ca[2] * R01[k][j];
      M2im[k][j] = -sa[2] * R01[3 - k][j];
    }
  float M3re[4][4], M3im[4][4];
  #pragma unroll
  for (int i = 0; i < 4; ++i)
    #pragma unroll
    for (int j = 0; j < 4; ++j) {
      float rr = 0.f, ii = 0.f;
      #pragma unroll
      for (int k = 0; k < 4; ++k) {
        rr += R34[i][k] * M2re[k][j];
        ii += R34[i][k] * M2im[k][j];
      }
      M3re[i][j] = rr;
      M3im[i][j] = ii;
    }
  #pragma unroll
  for (int k = 0; k < 4; ++k)
    #pragma unroll
    for (int j = 0; j < 4; ++j) {
      float vre = ca[5] * M3re[k][j] + sa[5] * M3im[3 - k][j];
      float vim = ca[5] * M3im[k][j] - sa[5] * M3re[3 - k][j];
      // W[j][k] = V[k][j] (conj for pass 0)
      float wim = (pass == 0) ? -vim : vim;
      Wre2[j][k] = rflu(h2u(__floats2half2_rn(vre, vre)));
      Wimn[j][k] = rflu(h2u(__floats2half2_rn(-wim, wim)));
      Wri[j][k] = rflu(h2u(__floats2half2_rn(vre, wim)));
    }
}

// One pass over a 1024 x 8 column block; result written TRANSPOSED.
// 3-phase structure (2 barriers): phase0 = global load + digit-0 (stride 256)
// in registers + LDS stage; S1 = digits 1,2 (strides 64,16); S2 = digits 3,4
// (strides 4,1) + transposed writeout. Digit transforms commute.
// PASS 0: src = X (fp32, batch bg), dst = ws (complex fp16, chunk-local bl)
// PASS 1: src = ws (complex fp16, bl), dst = d_out fp32 real/imag planes (bg)
// NOTE: min-waves/EU stays 4 — demanding 8 caps VGPRs at 64 and spills
// (R4: VGPR=32, WRITE_SIZE 137 MB, 2x slowdown).
template <int PASS>
__global__ __launch_bounds__(512, 4) void qpass(const void* __restrict__ srcv,
                                                const float* __restrict__ weight,
                                                void* __restrict__ dstv,
                                                int batch0) {
  __shared__ __half2 tile[DIM * LSTRIDE];
  const int t = threadIdx.x;

  int B = blockIdx.x;
  int total = gridDim.x;
  int L;
  if ((total & 7) == 0) {
    int q = total >> 3;
    L = (B & 7) * q + (B >> 3);
  } else {
    L = B;
  }
  const int cg = L & 127;        // column group within batch (128 x 8 cols)
  const int bl = L >> 7;         // chunk-local batch (ws index)
  const int bg = batch0 + bl;    // global batch (x / out index)
  const int c0 = cg * CBLK;

  unsigned Wre2[4][4], Wimn[4][4], Wri[4][4];
  compute_W(weight, PASS, Wre2, Wimn, Wri);

  // ---- phase 0: load + digit 0 (stride 256) + stage ----
  {
    const int r0 = t >> 1, h = (t & 1) * 4;  // rows r0+256k, cols h..h+3
    __half2 o[4][4];  // o[p][j] = output row r0+256p, col h+j
    if (PASS == 0) {
      const float* s = (const float*)srcv + (size_t)bg * DIM * DIM + c0 + h;
      float4 ld[4];
      #pragma unroll
      for (int k = 0; k < 4; ++k)
        ld[k] = *reinterpret_cast<const float4*>(s + (size_t)(r0 + 256 * k) * DIM);
      __half2 xh[4][4];  // (re,re)
      #pragma unroll
      for (int k = 0; k < 4; ++k) {
        xh[k][0] = __half2half2(__float2half(ld[k].x));
        xh[k][1] = __half2half2(__float2half(ld[k].y));
        xh[k][2] = __half2half2(__float2half(ld[k].z));
        xh[k][3] = __half2half2(__float2half(ld[k].w));
      }
      #pragma unroll
      for (int j = 0; j < 4; ++j) {
        __half2 x[4] = {xh[0][j], xh[1][j], xh[2][j], xh[3][j]};
        __half2 y[4];
        mv4rp(x, y, Wri);
        #pragma unroll
        for (int p = 0; p < 4; ++p) o[p][j] = y[p];
      }
    } else {
      const __half2* s = (const __half2*)srcv + ((size_t)bl << 20) + c0 + h;
      H2x4 ld[4];
      #pragma unroll
      for (int k = 0; k < 4; ++k)
        ld[k] = *reinterpret_cast<const H2x4*>(s + (size_t)(r0 + 256 * k) * DIM);
      #pragma unroll
      for (int j = 0; j < 4; ++j) {
        __half2 x[4] = {ld[0].h[j], ld[1].h[j], ld[2].h[j], ld[3].h[j]};
        mv4p(x, 1, Wre2, Wimn);
        #pragma unroll
        for (int p = 0; p < 4; ++p) o[p][j] = x[p];
      }
    }
    #pragma unroll
    for (int p = 0; p < 4; ++p)
      #pragma unroll
      for (int j = 0; j < 4; ++j)
        tile[lidx(r0 + 256 * p, h + j)] = o[p][j];
  }
  __syncthreads();

  // ---- S1: digits 1,2 (row strides 64, 16) ---- 1 item/thread
  {
    int c = t & 7, gg = t >> 3;           // gg in [0,64)
    int base = (gg >> 4) * 256 + (gg & 15);  // fixed d0 (gg>>4), low4 (gg&15)
    __half2 v[16];
    #pragma unroll
    for (int k1 = 0; k1 < 4; ++k1)
      #pragma unroll
      for (int k2 = 0; k2 < 4; ++k2)
        v[k1 * 4 + k2] = tile[lidx(base + k1 * 64 + k2 * 16, c)];
    #pragma unroll
    for (int k1 = 0; k1 < 4; ++k1) mv4p(&v[k1 * 4], 1, Wre2, Wimn);  // digit 2
    #pragma unroll
    for (int k2 = 0; k2 < 4; ++k2) mv4p(&v[k2], 4, Wre2, Wimn);      // digit 1
    #pragma unroll
    for (int k1 = 0; k1 < 4; ++k1)
      #pragma unroll
      for (int k2 = 0; k2 < 4; ++k2)
        tile[lidx(base + k1 * 64 + k2 * 16, c)] = v[k1 * 4 + k2];
  }
  __syncthreads();

  // ---- S2: digits 3,4 (row strides 4, 1) + transposed writeout ----
  {
    int c = t & 7, q = t >> 3;  // rows 16q..16q+15, column c
    __half2 v[16];
    #pragma unroll
    for (int k = 0; k < 16; ++k) v[k] = tile[lidx(16 * q + k, c)];
    #pragma unroll
    for (int k3 = 0; k3 < 4; ++k3) mv4p(&v[4 * k3], 1, Wre2, Wimn);  // digit 4
    #pragma unroll
    for (int k4 = 0; k4 < 4; ++k4) mv4p(&v[k4], 4, Wre2, Wimn);      // digit 3
    if (PASS == 0) {
      // ws layout: complex-fp16 Tt[bl][k=c0+c][i=16q..16q+15] — 64 B/lane
      __half2* d = (__half2*)dstv + ((size_t)bl << 20) + (size_t)(c0 + c) * DIM + 16 * q;
      #pragma unroll
      for (int g4 = 0; g4 < 4; ++g4) {
        H2x4 o;
        o.h[0] = v[4 * g4 + 0];
        o.h[1] = v[4 * g4 + 1];
        o.h[2] = v[4 * g4 + 2];
        o.h[3] = v[4 * g4 + 3];
        *reinterpret_cast<H2x4*>(d + 4 * g4) = o;
      }
    } else {
      // out[0][bg][i=c0+c][j=16q..16q+15] (real), out[1][...] (imag)
      float* dr = (float*)dstv + ((size_t)bg << 20) + (size_t)(c0 + c) * DIM + 16 * q;
      float* di = dr + ((size_t)1 << 23);
      #pragma unroll
      for (int g4 = 0; g4 < 4; ++g4) {
        float2 f0 = __half22float2(v[4 * g4 + 0]);
        float2 f1 = __half22float2(v[4 * g4 + 1]);
        float2 f2 = __half22float2(v[4 * g4 + 2]);
        float2 f3 = __half22float2(v[4 * g4 + 3]);
        vfloat4 re = {f0.x, f1.x, f2.x, f3.x};
        vfloat4 im = {f0.y, f1.y, f2.y, f3.y};
        __builtin_nontemporal_store(re, reinterpret_cast<vfloat4*>(dr + 4 * g4));
        __builtin_nontemporal_store(im, reinterpret_cast<vfloat4*>(di + 4 * g4));
      }
    }
  }
}

extern "C" void kernel_launch(void* const* d_in, const int* in_sizes, int n_in,
                              void* d_out, int out_size, void* d_ws, size_t ws_size,
                              hipStream_t stream) {
  const float* x = (const float*)d_in[0];
  const float* w = (const float*)d_in[1];

  const size_t per_batch = (size_t)DIM * DIM * sizeof(__half2);  // 4 MB complex fp16
  int max_nb = (int)(ws_size / per_batch);
  if (max_nb > NB) max_nb = NB;
  if (max_nb < 1) max_nb = 1;  // assume ws >= 4 MB

  for (int b0 = 0; b0 < NB; b0 += max_nb) {
    int nb = NB - b0 < max_nb ? NB - b0 : max_nb;
    dim3 grid(128 * nb);
    qpass<0><<<grid, 512, 0, stream>>>(x, w, d_ws, b0);
    qpass<1><<<grid, 512, 0, stream>>>(d_ws, w, d_out, b0);
  }
}